// Round 12
// baseline (528.464 us; speedup 1.0000x reference)
//
#include <hip/hip_runtime.h>

typedef __attribute__((ext_vector_type(8))) short bf16x8;
typedef __attribute__((ext_vector_type(4))) float f32x4;
typedef unsigned short ushort_t;
typedef unsigned int uint_t;

#define DEV static __device__ __forceinline__

constexpr int Bc = 2, Tc = 2048, Dc = 2048, Hc = 16, HDc = 128;
constexpr int MTOK = Bc * Tc;                       // 4096 tokens
constexpr float SCALE = 0.08838834764831845f;       // HD^-0.5

DEV ushort_t f2bf(float f) {
    uint_t x = __builtin_bit_cast(uint_t, f);
    uint_t r = (x + 0x7fffu + ((x >> 16) & 1u)) >> 16;   // RNE
    return (ushort_t)r;
}
DEV float bf2f(ushort_t u) {
    uint_t x = ((uint_t)u) << 16;
    return __builtin_bit_cast(float, x);
}

// async global->LDS, 16B per lane; lds dest = wave-uniform base + lane*16
DEV void gload16(const void* g, void* l) {
    __builtin_amdgcn_global_load_lds(
        (const __attribute__((address_space(1))) void*)g,
        (__attribute__((address_space(3))) void*)l, 16, 0, 0);
}

// ---------------- f32 -> bf16 cast, 8 elems/thread ----------------
__global__ __launch_bounds__(256) void cast_kernel(const float* __restrict__ in,
                                                   ushort_t* __restrict__ out, int n8) {
    int i = blockIdx.x * 256 + threadIdx.x;
    if (i >= n8) return;
    const float4* p = reinterpret_cast<const float4*>(in);
    float4 a = p[2 * i], b = p[2 * i + 1];
    uint4 o;
    o.x = (uint_t)f2bf(a.x) | ((uint_t)f2bf(a.y) << 16);
    o.y = (uint_t)f2bf(a.z) | ((uint_t)f2bf(a.w) << 16);
    o.z = (uint_t)f2bf(b.x) | ((uint_t)f2bf(b.y) << 16);
    o.w = (uint_t)f2bf(b.z) | ((uint_t)f2bf(b.w) << 16);
    reinterpret_cast<uint4*>(out)[i] = o;
}

// ---------------- RoPE (in-place on bf16 [B,T,H,HD]), 4 pairs/thread ----------------
__global__ __launch_bounds__(256) void rope_kernel(ushort_t* __restrict__ X,
                                                   const float* __restrict__ fc,
                                                   float mul, int n8) {
    int idx = blockIdx.x * 256 + threadIdx.x;
    if (idx >= n8) return;
    int g = idx & (Dc / 8 - 1);              // 8-elem group within row (0..255)
    int t = (idx >> 8) & (Tc - 1);           // token position
    int i0 = (g & (HDc / 8 - 1)) * 4;        // pair index base within head
    uint4 raw = reinterpret_cast<uint4*>(X)[idx];
    uint_t w[4] = {raw.x, raw.y, raw.z, raw.w};
    const float2* f2 = reinterpret_cast<const float2*>(fc) + (size_t)t * (HDc / 2) + i0;
    uint_t res[4];
#pragma unroll
    for (int j = 0; j < 4; ++j) {
        float x0 = bf2f((ushort_t)(w[j] & 0xffffu));
        float x1 = bf2f((ushort_t)(w[j] >> 16));
        float2 cs = f2[j];
        float y0 = (x0 * cs.x - x1 * cs.y) * mul;
        float y1 = (x0 * cs.y + x1 * cs.x) * mul;
        res[j] = (uint_t)f2bf(y0) | ((uint_t)f2bf(y1) << 16);
    }
    uint4 o; o.x = res[0]; o.y = res[1]; o.z = res[2]; o.w = res[3];
    reinterpret_cast<uint4*>(X)[idx] = o;
}

// ---------------- GEMM: C[M,N] = A[M,K] * Bw[N,K]^T  (both K-contiguous) ----------------
// m97 structure: linear LDS [128][64] (NO pad — required by global_load_lds),
// width-16 async staging, ds_read_b128 fragments, 2x2 waves x 4x4 16x16 frags.
// MODE 0: bf16 row-major out; MODE 1: f32 row-major out; MODE 2: bf16 out transposed as
//         vT[b][h][hd][t]  (for attention's PV B-operand)
template <int MODE>
__global__ __launch_bounds__(256) void gemm_bt(const ushort_t* __restrict__ A,
                                               const ushort_t* __restrict__ Bw,
                                               void* __restrict__ Cout,
                                               int M, int N, int K) {
    __shared__ ushort_t As[128][64];
    __shared__ ushort_t Bs[128][64];

    const int tid = threadIdx.x;
    const int lane = tid & 63;
    const int wave = tid >> 6;               // 0..3
    const int wm = wave >> 1, wn = wave & 1; // 2x2 wave grid, 64x64 each
    const int m0 = blockIdx.y * 128, n0 = blockIdx.x * 128;
    const int fr = lane & 15, fg = lane >> 4;

    // staging geometry: 1KB chunk per wave-instruction = 8 rows x 128B
    // lane i covers row chunk*8 + i/8, col elems 8*(i%8)
    const int srow = lane >> 3;              // 0..7 row within chunk
    const int scol = (lane & 7) * 8;         // elem col within row

    f32x4 acc[4][4];
#pragma unroll
    for (int mi = 0; mi < 4; ++mi)
#pragma unroll
        for (int ni = 0; ni < 4; ++ni)
#pragma unroll
            for (int i = 0; i < 4; ++i) acc[mi][ni][i] = 0.f;

    for (int k0 = 0; k0 < K; k0 += 64) {
        __syncthreads();
#pragma unroll
        for (int r = 0; r < 4; ++r) {
            const int chunk = wave * 4 + r;       // 0..15
            const int row = chunk * 8 + srow;     // 0..127
            gload16(&A[(size_t)(m0 + row) * K + k0 + scol], &As[chunk * 8][0]);
            gload16(&Bw[(size_t)(n0 + row) * K + k0 + scol], &Bs[chunk * 8][0]);
        }
        __syncthreads();   // drains vmcnt -> tiles visible
#pragma unroll
        for (int kk = 0; kk < 64; kk += 32) {
            bf16x8 a[4], b[4];
#pragma unroll
            for (int mi = 0; mi < 4; ++mi)
                a[mi] = *reinterpret_cast<const bf16x8*>(&As[64 * wm + 16 * mi + fr][kk + 8 * fg]);
#pragma unroll
            for (int ni = 0; ni < 4; ++ni)
                b[ni] = *reinterpret_cast<const bf16x8*>(&Bs[64 * wn + 16 * ni + fr][kk + 8 * fg]);
#pragma unroll
            for (int mi = 0; mi < 4; ++mi)
#pragma unroll
                for (int ni = 0; ni < 4; ++ni)
                    acc[mi][ni] = __builtin_amdgcn_mfma_f32_16x16x32_bf16(a[mi], b[ni], acc[mi][ni], 0, 0, 0);
        }
    }

#pragma unroll
    for (int mi = 0; mi < 4; ++mi)
#pragma unroll
        for (int ni = 0; ni < 4; ++ni)
#pragma unroll
            for (int i = 0; i < 4; ++i) {
                int row = m0 + 64 * wm + 16 * mi + 4 * fg + i;   // token / M index
                int col = n0 + 64 * wn + 16 * ni + fr;           // out-dim / N index
                float v = acc[mi][ni][i];
                if (MODE == 0) {
                    ((ushort_t*)Cout)[(size_t)row * N + col] = f2bf(v);
                } else if (MODE == 1) {
                    ((float*)Cout)[(size_t)row * N + col] = v;
                } else {
                    int b = row >> 11, t = row & (Tc - 1);
                    int h = col >> 7, hd = col & (HDc - 1);
                    ((ushort_t*)Cout)[(((size_t)b * Hc + h) * HDc + hd) * Tc + t] = f2bf(v);
                }
            }
}

// ---------------- Flash attention: 64 Q-rows/block (4 waves x 16), 64-key tiles --------
__global__ __launch_bounds__(256) void attn_kernel(const ushort_t* __restrict__ Q,
                                                   const ushort_t* __restrict__ Kt,
                                                   const ushort_t* __restrict__ Vt,
                                                   ushort_t* __restrict__ O) {
    __shared__ ushort_t Ks[64][136];      // [key][hd], +8 pad
    __shared__ ushort_t Vs[128][72];      // [hd][key], +8 pad
    __shared__ ushort_t Ps[4][16][72];    // per-wave P tile [q][key], +8 pad

    const int tid = threadIdx.x;
    const int lane = tid & 63;
    const int wave = tid >> 6;
    const int bh = blockIdx.y;
    const int b = bh / Hc, h = bh % Hc;
    const int q0 = blockIdx.x * 64;
    const int fr = lane & 15, fg = lane >> 4;

    const size_t base = ((size_t)b * Tc) * Dc + (size_t)h * HDc;     // for Q/K/O [B,T,H,HD]
    const size_t vbase = (((size_t)b * Hc + h) * HDc) * Tc;          // for Vt [B,H,HD,T]

    // Q fragments held in registers: rows q0+16*wave+fr, k = 32*kc + 8*fg
    bf16x8 qf[4];
    const int qrow = q0 + 16 * wave + fr;
#pragma unroll
    for (int kc = 0; kc < 4; ++kc)
        qf[kc] = *reinterpret_cast<const bf16x8*>(&Q[base + (size_t)qrow * Dc + kc * 32 + 8 * fg]);

    float mrow[4], lsum[4];
#pragma unroll
    for (int i = 0; i < 4; ++i) { mrow[i] = -1e30f; lsum[i] = 0.f; }
    f32x4 accO[8];
#pragma unroll
    for (int hb = 0; hb < 8; ++hb)
#pragma unroll
        for (int i = 0; i < 4; ++i) accO[hb][i] = 0.f;

    const int krow = tid >> 4, kcb = tid & 15;   // K staging: 64 rows x 16 chunks
    const int vrow = tid >> 3, vcb = tid & 7;    // V staging: 128 rows x 8 chunks

    for (int kt = 0; kt < Tc / 64; ++kt) {
        __syncthreads();
#pragma unroll
        for (int rr = 0; rr < 4; ++rr) {
            int row = krow + 16 * rr;
            *reinterpret_cast<uint4*>(&Ks[row][kcb * 8]) =
                *reinterpret_cast<const uint4*>(&Kt[base + (size_t)(kt * 64 + row) * Dc + kcb * 8]);
            int hdr = vrow + 32 * rr;
            *reinterpret_cast<uint4*>(&Vs[hdr][vcb * 8]) =
                *reinterpret_cast<const uint4*>(&Vt[vbase + (size_t)hdr * Tc + kt * 64 + vcb * 8]);
        }
        __syncthreads();

        // S = Q K^T  (16x64 per wave)
        f32x4 accS[4];
#pragma unroll
        for (int n = 0; n < 4; ++n) {
#pragma unroll
            for (int i = 0; i < 4; ++i) accS[n][i] = 0.f;
#pragma unroll
            for (int kc = 0; kc < 4; ++kc) {
                bf16x8 kf = *reinterpret_cast<const bf16x8*>(&Ks[16 * n + fr][kc * 32 + 8 * fg]);
                accS[n] = __builtin_amdgcn_mfma_f32_16x16x32_bf16(qf[kc], kf, accS[n], 0, 0, 0);
            }
        }

        // online softmax (row r = 4*fg + i, cols spread over 16 lanes x 4 frags)
        float fac[4];
#pragma unroll
        for (int i = 0; i < 4; ++i) {
            float v = fmaxf(fmaxf(accS[0][i], accS[1][i]), fmaxf(accS[2][i], accS[3][i]));
#pragma unroll
            for (int off = 1; off < 16; off <<= 1) v = fmaxf(v, __shfl_xor(v, off, 64));
            float mn = fmaxf(mrow[i], v);
            fac[i] = __expf(mrow[i] - mn);
            mrow[i] = mn;
        }
        float psum[4] = {0.f, 0.f, 0.f, 0.f};
#pragma unroll
        for (int n = 0; n < 4; ++n)
#pragma unroll
            for (int i = 0; i < 4; ++i) {
                float pv = __expf(accS[n][i] - mrow[i]);
                accS[n][i] = pv;
                psum[i] += pv;
            }
#pragma unroll
        for (int i = 0; i < 4; ++i) {
#pragma unroll
            for (int off = 1; off < 16; off <<= 1) psum[i] += __shfl_xor(psum[i], off, 64);
            lsum[i] = lsum[i] * fac[i] + psum[i];
        }
#pragma unroll
        for (int hb = 0; hb < 8; ++hb)
#pragma unroll
            for (int i = 0; i < 4; ++i) accO[hb][i] *= fac[i];

        // P (C-layout) -> LDS -> A-fragments
#pragma unroll
        for (int n = 0; n < 4; ++n)
#pragma unroll
            for (int i = 0; i < 4; ++i)
                Ps[wave][4 * fg + i][16 * n + fr] = f2bf(accS[n][i]);
        __syncthreads();
        bf16x8 pf[2];
#pragma unroll
        for (int kc = 0; kc < 2; ++kc)
            pf[kc] = *reinterpret_cast<const bf16x8*>(&Ps[wave][fr][kc * 32 + 8 * fg]);
#pragma unroll
        for (int hb = 0; hb < 8; ++hb) {
#pragma unroll
            for (int kc = 0; kc < 2; ++kc) {
                bf16x8 vf = *reinterpret_cast<const bf16x8*>(&Vs[16 * hb + fr][kc * 32 + 8 * fg]);
                accO[hb] = __builtin_amdgcn_mfma_f32_16x16x32_bf16(pf[kc], vf, accO[hb], 0, 0, 0);
            }
        }
    }

#pragma unroll
    for (int hb = 0; hb < 8; ++hb)
#pragma unroll
        for (int i = 0; i < 4; ++i) {
            int row = q0 + 16 * wave + 4 * fg + i;
            O[base + (size_t)row * Dc + 16 * hb + fr] = f2bf(accO[hb][i] / lsum[i]);
        }
}

// ---------------- launch ----------------
// Workspace budget: 40 MB (was 96 MB).  Layout:
//   ws + 0        : xb   16 MB  (bf16 x; later reused as attention output)
//   ws + 16 MB    : wb    8 MB  (shared weight buffer, cast sequentially)
//   ws + 24 MB    : vtb  16 MB  (V^T)
// Q and K are staged in d_out (33.55 MB = exactly 2 x 16.78 MB); they are fully
// written by the Q/K GEMMs and fully consumed by attn_kernel BEFORE the final
// GEMM overwrites d_out.  All reuse hazards are same-stream serialized.
extern "C" void kernel_launch(void* const* d_in, const int* in_sizes, int n_in,
                              void* d_out, int out_size, void* d_ws, size_t ws_size,
                              hipStream_t stream) {
    const float* x  = (const float*)d_in[0];
    const float* fc = (const float*)d_in[1];
    const float* wq = (const float*)d_in[2];
    const float* wk = (const float*)d_in[3];
    const float* wv = (const float*)d_in[4];
    const float* wo = (const float*)d_in[5];
    float* out = (float*)d_out;

    char* p = (char*)d_ws;
    const size_t SZ_X = (size_t)MTOK * Dc * 2;   // 16,777,216 B
    const size_t SZ_W = (size_t)Dc * Dc * 2;     //  8,388,608 B
    ushort_t* xb  = (ushort_t*)(p);              // x bf16; later attn output
    ushort_t* wb  = (ushort_t*)(p + SZ_X);       // shared weight buffer
    ushort_t* vtb = (ushort_t*)(p + SZ_X + SZ_W);
    ushort_t* qb  = (ushort_t*)d_out;                      // Q in d_out[0:16MB)
    ushort_t* kb  = (ushort_t*)d_out + (SZ_X / 2);         // K in d_out[16:33.5MB)
    ushort_t* attnb = xb;   // attn output reuses xb (x dead after V GEMM)

    const int n8x = MTOK * Dc / 8;   // 1,048,576
    const int n8w = Dc * Dc / 8;     //   524,288
    dim3 gg(Dc / 128, MTOK / 128);

    cast_kernel<<<n8x / 256, 256, 0, stream>>>(x, xb, n8x);

    cast_kernel<<<n8w / 256, 256, 0, stream>>>(wq, wb, n8w);
    gemm_bt<0><<<gg, 256, 0, stream>>>(xb, wb, qb, MTOK, Dc, Dc);

    cast_kernel<<<n8w / 256, 256, 0, stream>>>(wk, wb, n8w);
    gemm_bt<0><<<gg, 256, 0, stream>>>(xb, wb, kb, MTOK, Dc, Dc);

    cast_kernel<<<n8w / 256, 256, 0, stream>>>(wv, wb, n8w);
    gemm_bt<2><<<gg, 256, 0, stream>>>(xb, wb, vtb, MTOK, Dc, Dc);

    rope_kernel<<<n8x / 256, 256, 0, stream>>>(qb, fc, SCALE, n8x);
    rope_kernel<<<n8x / 256, 256, 0, stream>>>(kb, fc, 1.0f, n8x);

    attn_kernel<<<dim3(Tc / 64, Bc * Hc), 256, 0, stream>>>(qb, kb, vtb, attnb);

    cast_kernel<<<n8w / 256, 256, 0, stream>>>(wo, wb, n8w);
    gemm_bt<1><<<gg, 256, 0, stream>>>(attnb, wb, out, MTOK, Dc, Dc);
}